// Round 1
// baseline (375.008 us; speedup 1.0000x reference)
//
#include <hip/hip_runtime.h>
#include <math.h>

#define BB 8
#define TT 4096
#define TP1 4097
#define HH 1024
#define NHD 16

__device__ __forceinline__ float dot4(const float4& a, const float4& b) {
  return a.x*b.x + a.y*b.y + a.z*b.z + a.w*b.w;
}

// K1: qbuf[b][j] = 0.125f * (cell[b,:]·Wq[j,:] + bq[j])   (1/8 = 1/sqrt(64) folded in)
// grid 64 (j-tiles of 16), block 256 = 16 jj x 16 qq
__global__ __launch_bounds__(256) void k_q(const float* __restrict__ cell,
                                           const float* __restrict__ Wq,
                                           const float* __restrict__ bq,
                                           float* __restrict__ qbuf) {
  __shared__ float cs[BB * HH];  // 32 KB
  int tid = threadIdx.x;
  #pragma unroll
  for (int m = 0; m < 8; m++) {
    int idx4 = tid + 256 * m;
    ((float4*)cs)[idx4] = ((const float4*)cell)[idx4];
  }
  __syncthreads();
  int jj = tid >> 4, qq = tid & 15;
  int j = blockIdx.x * 16 + jj;
  float acc[BB];
  #pragma unroll
  for (int b = 0; b < BB; b++) acc[b] = 0.f;
  #pragma unroll
  for (int k = 0; k < 16; k++) {
    int i = qq * 4 + 64 * k;
    float4 w = *(const float4*)&Wq[(size_t)j * HH + i];
    #pragma unroll
    for (int b = 0; b < BB; b++) {
      float4 c = *(const float4*)&cs[b * HH + i];
      acc[b] += dot4(w, c);
    }
  }
  #pragma unroll
  for (int b = 0; b < BB; b++) {
    acc[b] += __shfl_xor(acc[b], 1);
    acc[b] += __shfl_xor(acc[b], 2);
    acc[b] += __shfl_xor(acc[b], 4);
    acc[b] += __shfl_xor(acc[b], 8);
  }
  if (qq == 0) {
    float bqv = bq[j];
    #pragma unroll
    for (int b = 0; b < BB; b++) qbuf[b * HH + j] = 0.125f * (acc[b] + bqv);
  }
}

// K2: qWk[b][h][i] = sum_d qbuf[b][h*64+d] * Wk[h*64+d][i];  qbk[b][h] = q_head·bk_head
// grid 64 = h(16) x ic(4), block 256 (one i per thread)
__global__ __launch_bounds__(256) void k_qwk(const float* __restrict__ qbuf,
                                             const float* __restrict__ Wk,
                                             const float* __restrict__ bk,
                                             float* __restrict__ qWk,
                                             float* __restrict__ qbk) {
  __shared__ float q_s[BB * 64];
  __shared__ float bk_s[64];
  int tid = threadIdx.x;
  int h = blockIdx.x >> 2, ic = blockIdx.x & 3;
  if (tid < 128) {
    int b = tid >> 4, d4 = tid & 15;
    *(float4*)&q_s[b * 64 + d4 * 4] = *(const float4*)&qbuf[b * HH + h * 64 + d4 * 4];
  }
  if (tid >= 128 && tid < 144) {
    int d4 = tid - 128;
    *(float4*)&bk_s[d4 * 4] = *(const float4*)&bk[h * 64 + d4 * 4];
  }
  __syncthreads();
  int i = ic * 256 + tid;
  float acc[BB];
  #pragma unroll
  for (int b = 0; b < BB; b++) acc[b] = 0.f;
  for (int d = 0; d < 64; d++) {
    float wk = Wk[(size_t)(h * 64 + d) * HH + i];
    #pragma unroll
    for (int b = 0; b < BB; b++) acc[b] += q_s[b * 64 + d] * wk;
  }
  #pragma unroll
  for (int b = 0; b < BB; b++) qWk[(size_t)(b * NHD + h) * HH + i] = acc[b];
  if (ic == 0 && tid < 8) {
    float s = 0.f;
    for (int d = 0; d < 64; d++) s += q_s[tid * 64 + d] * bk_s[d];
    qbk[tid * NHD + h] = s;
  }
}

// K3: for each (b,t): e[h] = mask ? exp(kv·qWk[b,h] + qbk[b,h]) : 0
// writes probsT[b][t][16] (unnormalized) and per-tile head sums Spart.
// grid 512 = b(8) x t-tile(64 rows), block 256 = 64 rows x 4 quarters
__global__ __launch_bounds__(256) void k_scores(const float* __restrict__ hid,
                                                const float* __restrict__ qWk,
                                                const float* __restrict__ qbk,
                                                const int* __restrict__ mask,
                                                float* __restrict__ probsT,
                                                float* __restrict__ Spart) {
  __shared__ float kv_s[64 * 68];   // +4 pad: conflict-free per-row reads
  __shared__ float qw_s[16 * 68];
  __shared__ float e_s[64 * 17];
  __shared__ float qbk_s[16];
  int tid = threadIdx.x;
  int b = blockIdx.x >> 6, bt = blockIdx.x & 63;
  int t0 = bt * 64;
  if (tid < 16) qbk_s[tid] = qbk[b * NHD + tid];
  float acc[NHD];
  #pragma unroll
  for (int h = 0; h < NHD; h++) acc[h] = 0.f;
  int row = tid >> 2, qq = tid & 3;
  for (int c = 0; c < 16; c++) {
    __syncthreads();
    #pragma unroll
    for (int m = 0; m < 4; m++) {  // stage 64x64 kv tile, coalesced
      int idx4 = tid + 256 * m;
      int r = idx4 >> 4, c4 = idx4 & 15;
      float4 v = *(const float4*)&hid[(size_t)(b * TP1 + t0 + r) * HH + c * 64 + c4 * 4];
      *(float4*)&kv_s[r * 68 + c4 * 4] = v;
    }
    {  // stage 16x64 qWk slice
      int hh = tid >> 4, c4 = tid & 15;
      float4 v = *(const float4*)&qWk[(size_t)(b * NHD + hh) * HH + c * 64 + c4 * 4];
      *(float4*)&qw_s[hh * 68 + c4 * 4] = v;
    }
    __syncthreads();
    float4 kv4[4];
    #pragma unroll
    for (int k = 0; k < 4; k++) kv4[k] = *(const float4*)&kv_s[row * 68 + (qq + 4 * k) * 4];
    #pragma unroll
    for (int h = 0; h < NHD; h++) {
      #pragma unroll
      for (int k = 0; k < 4; k++) {
        float4 w = *(const float4*)&qw_s[h * 68 + (qq + 4 * k) * 4];
        acc[h] += dot4(kv4[k], w);
      }
    }
  }
  #pragma unroll
  for (int h = 0; h < NHD; h++) {  // reduce the 4 quarter-partials (adjacent lanes)
    acc[h] += __shfl_xor(acc[h], 1);
    acc[h] += __shfl_xor(acc[h], 2);
  }
  int t = t0 + row;
  int mk = mask[b * TT + t];
  float e[NHD];
  #pragma unroll
  for (int h = 0; h < NHD; h++) e[h] = mk ? __expf(acc[h] + qbk_s[h]) : 0.f;
  if (qq == 0) {
    float4* dst = (float4*)&probsT[(size_t)(b * TT + t) * NHD];
    dst[0] = make_float4(e[0], e[1], e[2], e[3]);
    dst[1] = make_float4(e[4], e[5], e[6], e[7]);
    dst[2] = make_float4(e[8], e[9], e[10], e[11]);
    dst[3] = make_float4(e[12], e[13], e[14], e[15]);
    #pragma unroll
    for (int h = 0; h < NHD; h++) e_s[row * 17 + h] = e[h];
  }
  __syncthreads();
  if (tid < 64) {  // per-head column sums over the 64 rows
    int g = tid >> 4, h2 = tid & 15;
    float s = 0.f;
    #pragma unroll
    for (int j = 0; j < 16; j++) s += e_s[(g + 4 * j) * 17 + h2];
    s += __shfl_xor(s, 16);
    s += __shfl_xor(s, 32);
    if (tid < 16) Spart[(size_t)(b * 64 + bt) * NHD + h2] = s;
  }
}

// K4: Sinv[b][h] = 1 / sum_c Spart
__global__ void k_sinv(const float* __restrict__ Spart, float* __restrict__ Sinv) {
  int tid = threadIdx.x;  // 128
  int b = tid >> 4, h = tid & 15;
  float s = 0.f;
  for (int c = 0; c < 64; c++) s += Spart[(size_t)(b * 64 + c) * NHD + h];
  Sinv[tid] = 1.f / s;
}

// K5: ctxin[b][h][i] = sum_t probsT[b][t][h] * kv[b][t][i]   (unnormalized)
// grid 256 = b(8) x i-chunk(32 cols), block 256 = 8 tsub x 32 ii
__global__ __launch_bounds__(256) void k_ctx(const float* __restrict__ hid,
                                             const float* __restrict__ probsT,
                                             float* __restrict__ ctxin) {
  __shared__ float red[8 * 32 * NHD];  // 16 KB
  int tid = threadIdx.x;
  int b = blockIdx.x >> 5, ic = blockIdx.x & 31;
  int i0 = ic * 32;
  int tsub = tid >> 5, ii = tid & 31;
  float acc[NHD];
  #pragma unroll
  for (int h = 0; h < NHD; h++) acc[h] = 0.f;
  const float* hb = hid + (size_t)b * TP1 * HH + i0 + ii;
  const float4* pb = (const float4*)(probsT + (size_t)b * TT * NHD);
  #pragma unroll 4
  for (int it = 0; it < 512; it++) {
    int t = it * 8 + tsub;
    float kv = hb[(size_t)t * HH];
    float4 p0 = pb[t * 4 + 0];
    float4 p1 = pb[t * 4 + 1];
    float4 p2 = pb[t * 4 + 2];
    float4 p3 = pb[t * 4 + 3];
    acc[0] += kv * p0.x; acc[1] += kv * p0.y; acc[2]  += kv * p0.z; acc[3]  += kv * p0.w;
    acc[4] += kv * p1.x; acc[5] += kv * p1.y; acc[6]  += kv * p1.z; acc[7]  += kv * p1.w;
    acc[8] += kv * p2.x; acc[9] += kv * p2.y; acc[10] += kv * p2.z; acc[11] += kv * p2.w;
    acc[12]+= kv * p3.x; acc[13]+= kv * p3.y; acc[14] += kv * p3.z; acc[15] += kv * p3.w;
  }
  #pragma unroll
  for (int h4 = 0; h4 < 4; h4++)
    *(float4*)&red[(tsub * 32 + ii) * NHD + h4 * 4] =
        make_float4(acc[h4 * 4], acc[h4 * 4 + 1], acc[h4 * 4 + 2], acc[h4 * 4 + 3]);
  __syncthreads();
  #pragma unroll
  for (int r = 0; r < 2; r++) {
    int o = r * 256 + tid;
    int ii2 = o >> 4, h = o & 15;
    float s = 0.f;
    #pragma unroll
    for (int ts = 0; ts < 8; ts++) s += red[(ts * 32 + ii2) * NHD + h];
    ctxin[(size_t)(b * NHD + h) * HH + i0 + ii2] = s;
  }
}

// K6: out[b][h*64+d] = Sinv[b][h] * (Wv[h*64+d,:]·ctxin[b][h][:]) + bv[h*64+d]
// grid 64 (j-tiles of 16, each within one head), block 256 = 16 jj x 16 qq
__global__ __launch_bounds__(256) void k_out(const float* __restrict__ Wv,
                                             const float* __restrict__ bv,
                                             const float* __restrict__ ctxin,
                                             const float* __restrict__ Sinv,
                                             float* __restrict__ out) {
  __shared__ float cs[BB * HH];  // 32 KB: ctxin[0..7][h][:]
  int tid = threadIdx.x;
  int j0 = blockIdx.x * 16;
  int h = j0 >> 6;
  #pragma unroll
  for (int m = 0; m < 8; m++) {
    int idx4 = tid + 256 * m;
    int b = idx4 >> 8, i4 = idx4 & 255;
    ((float4*)cs)[idx4] = *(const float4*)&ctxin[(size_t)(b * NHD + h) * HH + i4 * 4];
  }
  __syncthreads();
  int jj = tid >> 4, qq = tid & 15;
  int j = j0 + jj;
  float acc[BB];
  #pragma unroll
  for (int b = 0; b < BB; b++) acc[b] = 0.f;
  #pragma unroll
  for (int k = 0; k < 16; k++) {
    int i = qq * 4 + 64 * k;
    float4 w = *(const float4*)&Wv[(size_t)j * HH + i];
    #pragma unroll
    for (int b = 0; b < BB; b++) {
      float4 c = *(const float4*)&cs[b * HH + i];
      acc[b] += dot4(w, c);
    }
  }
  #pragma unroll
  for (int b = 0; b < BB; b++) {
    acc[b] += __shfl_xor(acc[b], 1);
    acc[b] += __shfl_xor(acc[b], 2);
    acc[b] += __shfl_xor(acc[b], 4);
    acc[b] += __shfl_xor(acc[b], 8);
  }
  if (qq == 0) {
    float bvj = bv[j];
    #pragma unroll
    for (int b = 0; b < BB; b++)
      out[b * HH + j] = Sinv[b * NHD + h] * acc[b] + bvj;
  }
}

extern "C" void kernel_launch(void* const* d_in, const int* in_sizes, int n_in,
                              void* d_out, int out_size, void* d_ws, size_t ws_size,
                              hipStream_t stream) {
  const float* hid  = (const float*)d_in[0];  // (8, 4097, 1024)
  const float* cell = (const float*)d_in[1];  // (8, 1024)
  const float* Wq   = (const float*)d_in[2];
  const float* bq   = (const float*)d_in[3];
  const float* Wk   = (const float*)d_in[4];
  const float* bk   = (const float*)d_in[5];
  const float* Wv   = (const float*)d_in[6];
  const float* bv   = (const float*)d_in[7];
  const int*  mask  = (const int*)d_in[8];    // (8, 4096)
  float* out = (float*)d_out;                 // (8, 1024)

  float* ws = (float*)d_ws;                   // ~3.2 MB total
  float* qbuf   = ws;             // 8192
  float* qWk    = ws + 8192;      // 131072
  float* qbk    = ws + 139264;    // 128
  float* probsT = ws + 139392;    // 524288  [b][t][16] unnormalized exp
  float* Spart  = ws + 663680;    // 8192
  float* Sinv   = ws + 671872;    // 128
  float* ctxin  = ws + 672000;    // 131072

  hipLaunchKernelGGL(k_q,      dim3(64),  dim3(256), 0, stream, cell, Wq, bq, qbuf);
  hipLaunchKernelGGL(k_qwk,    dim3(64),  dim3(256), 0, stream, qbuf, Wk, bk, qWk, qbk);
  hipLaunchKernelGGL(k_scores, dim3(512), dim3(256), 0, stream, hid, qWk, qbk, mask, probsT, Spart);
  hipLaunchKernelGGL(k_sinv,   dim3(1),   dim3(128), 0, stream, Spart, Sinv);
  hipLaunchKernelGGL(k_ctx,    dim3(256), dim3(256), 0, stream, hid, probsT, ctxin);
  hipLaunchKernelGGL(k_out,    dim3(64),  dim3(256), 0, stream, Wv, bv, ctxin, Sinv, out);
}

// Round 2
// 304.319 us; speedup vs baseline: 1.2323x; 1.2323x over previous
//
#include <hip/hip_runtime.h>
#include <math.h>

#define BB 8
#define TT 4096
#define TP1 4097
#define HH 1024
#define NHD 16

__device__ __forceinline__ float dot4(const float4& a, const float4& b) {
  return a.x*b.x + a.y*b.y + a.z*b.z + a.w*b.w;
}

// K1: qbuf[b][j] = 0.125f * (cell[b,:]·Wq[j,:] + bq[j])   (1/8 = 1/sqrt(64) folded in)
// grid 64 (j-tiles of 16), block 256 = 16 jj x 16 qq
__global__ __launch_bounds__(256) void k_q(const float* __restrict__ cell,
                                           const float* __restrict__ Wq,
                                           const float* __restrict__ bq,
                                           float* __restrict__ qbuf) {
  __shared__ float cs[BB * HH];  // 32 KB
  int tid = threadIdx.x;
  #pragma unroll
  for (int m = 0; m < 8; m++) {
    int idx4 = tid + 256 * m;
    ((float4*)cs)[idx4] = ((const float4*)cell)[idx4];
  }
  __syncthreads();
  int jj = tid >> 4, qq = tid & 15;
  int j = blockIdx.x * 16 + jj;
  float acc[BB];
  #pragma unroll
  for (int b = 0; b < BB; b++) acc[b] = 0.f;
  #pragma unroll
  for (int k = 0; k < 16; k++) {
    int i = qq * 4 + 64 * k;
    float4 w = *(const float4*)&Wq[(size_t)j * HH + i];
    #pragma unroll
    for (int b = 0; b < BB; b++) {
      float4 c = *(const float4*)&cs[b * HH + i];
      acc[b] += dot4(w, c);
    }
  }
  #pragma unroll
  for (int b = 0; b < BB; b++) {
    acc[b] += __shfl_xor(acc[b], 1);
    acc[b] += __shfl_xor(acc[b], 2);
    acc[b] += __shfl_xor(acc[b], 4);
    acc[b] += __shfl_xor(acc[b], 8);
  }
  if (qq == 0) {
    float bqv = bq[j];
    #pragma unroll
    for (int b = 0; b < BB; b++) qbuf[b * HH + j] = 0.125f * (acc[b] + bqv);
  }
}

// K2: qWkT[b][i][h] = sum_d qbuf[b][h*64+d] * Wk[h*64+d][i];  qbk[b][h] = q_head·bk_head
// grid 64 = h(16) x ic(4), block 256 (one i per thread). TRANSPOSED output [b][i][16].
__global__ __launch_bounds__(256) void k_qwk(const float* __restrict__ qbuf,
                                             const float* __restrict__ Wk,
                                             const float* __restrict__ bk,
                                             float* __restrict__ qWkT,
                                             float* __restrict__ qbk) {
  __shared__ float q_s[BB * 64];
  __shared__ float bk_s[64];
  int tid = threadIdx.x;
  int h = blockIdx.x >> 2, ic = blockIdx.x & 3;
  if (tid < 128) {
    int b = tid >> 4, d4 = tid & 15;
    *(float4*)&q_s[b * 64 + d4 * 4] = *(const float4*)&qbuf[b * HH + h * 64 + d4 * 4];
  }
  if (tid >= 128 && tid < 144) {
    int d4 = tid - 128;
    *(float4*)&bk_s[d4 * 4] = *(const float4*)&bk[h * 64 + d4 * 4];
  }
  __syncthreads();
  int i = ic * 256 + tid;
  float acc[BB];
  #pragma unroll
  for (int b = 0; b < BB; b++) acc[b] = 0.f;
  for (int d = 0; d < 64; d++) {
    float wk = Wk[(size_t)(h * 64 + d) * HH + i];
    #pragma unroll
    for (int b = 0; b < BB; b++) acc[b] += q_s[b * 64 + d] * wk;
  }
  #pragma unroll
  for (int b = 0; b < BB; b++) qWkT[((size_t)b * HH + i) * NHD + h] = acc[b];
  if (ic == 0 && tid < 8) {
    float s = 0.f;
    for (int d = 0; d < 64; d++) s += q_s[tid * 64 + d] * bk_s[d];
    qbk[tid * NHD + h] = s;
  }
}

// K3: e[b][t][h] = mask ? exp(kv_row·qWk[b,h] + qbk) : 0  (unnormalized)
// grid 512 = b(8) x ttile(64). block 256 = 4 waves; lane = t-row, wave = K-chunk of 256.
// qWkT reads are wave-uniform -> scalar loads; NO LDS in the hot loop.
__global__ __launch_bounds__(256) void k_scores(const float* __restrict__ hid,
                                                const float* __restrict__ qWkT,
                                                const float* __restrict__ qbk,
                                                const int* __restrict__ mask,
                                                float* __restrict__ probsT,
                                                float* __restrict__ Spart) {
  __shared__ float red[4 * 64 * NHD];  // 16 KB: per-wave K-partials
  __shared__ float e_s[64 * NHD];      // 4 KB
  __shared__ float qbk_s[NHD];
  int tid = threadIdx.x;
  int b = blockIdx.x >> 6, tile = blockIdx.x & 63;
  if (tid < NHD) qbk_s[tid] = qbk[b * NHD + tid];
  int w = __builtin_amdgcn_readfirstlane(tid >> 6);  // wave id -> uniform
  int lane = tid & 63;
  int t = tile * 64 + lane;
  const float4* rowp = (const float4*)(hid + (size_t)(b * TP1 + t) * HH + (w << 8));
  const float* qwt = qWkT + (size_t)((b << 10) + (w << 8)) * NHD;  // uniform base
  float acc[NHD];
  #pragma unroll
  for (int h = 0; h < NHD; h++) acc[h] = 0.f;
  #pragma unroll 2
  for (int ic = 0; ic < 64; ic++) {
    float4 kv = rowp[ic];
    const float* qp = qwt + (ic << 6);  // uniform: (4*ic+j)*16 + h
    #pragma unroll
    for (int h = 0; h < NHD; h++)
      acc[h] += kv.x * qp[h] + kv.y * qp[NHD + h] +
                kv.z * qp[2 * NHD + h] + kv.w * qp[3 * NHD + h];
  }
  #pragma unroll
  for (int h4 = 0; h4 < 4; h4++)
    *(float4*)&red[((w << 6) + lane) * NHD + (h4 << 2)] =
        make_float4(acc[h4 * 4], acc[h4 * 4 + 1], acc[h4 * 4 + 2], acc[h4 * 4 + 3]);
  __syncthreads();
  // combine the 4 K-chunk partials; thread: row = tid>>2, h-quad = tid&3
  int row = tid >> 2, hq = tid & 3;
  float4 s = make_float4(0.f, 0.f, 0.f, 0.f);
  #pragma unroll
  for (int ww = 0; ww < 4; ww++) {
    float4 r = *(const float4*)&red[((ww << 6) + row) * NHD + (hq << 2)];
    s.x += r.x; s.y += r.y; s.z += r.z; s.w += r.w;
  }
  int mk = mask[b * TT + tile * 64 + row];
  float4 e;
  e.x = mk ? __expf(s.x + qbk_s[hq * 4 + 0]) : 0.f;
  e.y = mk ? __expf(s.y + qbk_s[hq * 4 + 1]) : 0.f;
  e.z = mk ? __expf(s.z + qbk_s[hq * 4 + 2]) : 0.f;
  e.w = mk ? __expf(s.w + qbk_s[hq * 4 + 3]) : 0.f;
  *(float4*)&probsT[(size_t)(b * TT + tile * 64 + row) * NHD + (hq << 2)] = e;
  *(float4*)&e_s[row * NHD + (hq << 2)] = e;
  __syncthreads();
  if (tid < 64) {  // per-head sums over the 64 rows
    int g = tid >> 4, h2 = tid & 15;
    float s2 = 0.f;
    #pragma unroll
    for (int j = 0; j < 16; j++) s2 += e_s[((g + (j << 2)) << 4) + h2];
    s2 += __shfl_xor(s2, 16);
    s2 += __shfl_xor(s2, 32);
    if (tid < 16) Spart[(size_t)((b << 6) + tile) * NHD + h2] = s2;
  }
}

// K4: Sinv[b][h] = 1 / sum_c Spart
__global__ void k_sinv(const float* __restrict__ Spart, float* __restrict__ Sinv) {
  int tid = threadIdx.x;  // 128
  float s = 0.f;
  for (int c = 0; c < 64; c++) s += Spart[(size_t)((tid >> 4) * 64 + c) * NHD + (tid & 15)];
  Sinv[tid] = 1.f / s;
}

// K5: ctxpart[th][b][h][i] = sum_{t in half,wave} e[t][h] * kv[t][i]
// grid 256 = b(8) x ic(16) x th(2). block 256 = 4 waves; lane = i (coalesced kv),
// t wave-uniform -> probsT row via scalar loads.
__global__ __launch_bounds__(256) void k_ctx(const float* __restrict__ hid,
                                             const float* __restrict__ probsT,
                                             float* __restrict__ ctxpart) {
  __shared__ float red[4 * 64 * NHD];  // 16 KB
  int tid = threadIdx.x;
  int b = blockIdx.x >> 5, ic = (blockIdx.x >> 1) & 15, th = blockIdx.x & 1;
  int w = __builtin_amdgcn_readfirstlane(tid >> 6);
  int lane = tid & 63;
  int i = (ic << 6) + lane;
  const float* kvp = hid + (size_t)b * TP1 * HH + i;
  const float* pb = probsT + (size_t)b * TT * NHD;
  int t0 = (th << 11) + w;  // wave covers t = t0 + 4*it
  float acc[NHD];
  #pragma unroll
  for (int h = 0; h < NHD; h++) acc[h] = 0.f;
  #pragma unroll 4
  for (int it = 0; it < 512; it++) {
    int t = t0 + (it << 2);
    float kv = kvp[(size_t)t * HH];
    const float* pp = pb + t * NHD;  // uniform -> s_load
    #pragma unroll
    for (int h = 0; h < NHD; h++) acc[h] += kv * pp[h];
  }
  #pragma unroll
  for (int h4 = 0; h4 < 4; h4++)
    *(float4*)&red[((w << 6) + lane) * NHD + (h4 << 2)] =
        make_float4(acc[h4 * 4], acc[h4 * 4 + 1], acc[h4 * 4 + 2], acc[h4 * 4 + 3]);
  __syncthreads();
  int ii = tid >> 2, hq = tid & 3;
  float4 s = make_float4(0.f, 0.f, 0.f, 0.f);
  #pragma unroll
  for (int ww = 0; ww < 4; ww++) {
    float4 r = *(const float4*)&red[((ww << 6) + ii) * NHD + (hq << 2)];
    s.x += r.x; s.y += r.y; s.z += r.z; s.w += r.w;
  }
  size_t base = ((size_t)(th * BB + b) * NHD + (hq << 2)) * HH + (ic << 6) + ii;
  ctxpart[base] = s.x;
  ctxpart[base + HH] = s.y;
  ctxpart[base + 2 * HH] = s.z;
  ctxpart[base + 3 * HH] = s.w;
}

// K6: out[b][h*64+d] = Sinv[b][h] * (Wv[h*64+d,:]·ctxin[b][h][:]) + bv[h*64+d]
// ctxin = ctxpart[0] + ctxpart[1] summed during staging.
// grid 64 (j-tiles of 16, each within one head), block 256 = 16 jj x 16 qq
__global__ __launch_bounds__(256) void k_out(const float* __restrict__ Wv,
                                             const float* __restrict__ bv,
                                             const float* __restrict__ ctxpart,
                                             const float* __restrict__ Sinv,
                                             float* __restrict__ out) {
  __shared__ float cs[BB * HH];  // 32 KB: summed ctxin[0..7][h][:]
  int tid = threadIdx.x;
  int j0 = blockIdx.x * 16;
  int h = j0 >> 6;
  const float4* cp4 = (const float4*)ctxpart;
  #pragma unroll
  for (int m = 0; m < 8; m++) {
    int idx4 = tid + 256 * m;
    int b = idx4 >> 8, i4 = idx4 & 255;
    float4 p0 = cp4[(((size_t)(0 * BB + b) * NHD + h) << 8) + i4];
    float4 p1 = cp4[(((size_t)(1 * BB + b) * NHD + h) << 8) + i4];
    ((float4*)cs)[idx4] = make_float4(p0.x + p1.x, p0.y + p1.y, p0.z + p1.z, p0.w + p1.w);
  }
  __syncthreads();
  int jj = tid >> 4, qq = tid & 15;
  int j = j0 + jj;
  float acc[BB];
  #pragma unroll
  for (int b = 0; b < BB; b++) acc[b] = 0.f;
  #pragma unroll
  for (int k = 0; k < 16; k++) {
    int i = qq * 4 + 64 * k;
    float4 w = *(const float4*)&Wv[(size_t)j * HH + i];
    #pragma unroll
    for (int b = 0; b < BB; b++) {
      float4 c = *(const float4*)&cs[b * HH + i];
      acc[b] += dot4(w, c);
    }
  }
  #pragma unroll
  for (int b = 0; b < BB; b++) {
    acc[b] += __shfl_xor(acc[b], 1);
    acc[b] += __shfl_xor(acc[b], 2);
    acc[b] += __shfl_xor(acc[b], 4);
    acc[b] += __shfl_xor(acc[b], 8);
  }
  if (qq == 0) {
    float bvj = bv[j];
    #pragma unroll
    for (int b = 0; b < BB; b++)
      out[b * HH + j] = Sinv[b * NHD + h] * acc[b] + bvj;
  }
}

extern "C" void kernel_launch(void* const* d_in, const int* in_sizes, int n_in,
                              void* d_out, int out_size, void* d_ws, size_t ws_size,
                              hipStream_t stream) {
  const float* hid  = (const float*)d_in[0];  // (8, 4097, 1024)
  const float* cell = (const float*)d_in[1];  // (8, 1024)
  const float* Wq   = (const float*)d_in[2];
  const float* bq   = (const float*)d_in[3];
  const float* Wk   = (const float*)d_in[4];
  const float* bk   = (const float*)d_in[5];
  const float* Wv   = (const float*)d_in[6];
  const float* bv   = (const float*)d_in[7];
  const int*  mask  = (const int*)d_in[8];    // (8, 4096)
  float* out = (float*)d_out;                 // (8, 1024)

  float* ws = (float*)d_ws;                   // ~3.74 MB total
  float* qbuf    = ws;             // 8192
  float* qWkT    = ws + 8192;      // 131072  [b][i][16]
  float* qbk     = ws + 139264;    // 128
  float* probsT  = ws + 139392;    // 524288  [b][t][16] unnormalized exp
  float* Spart   = ws + 663680;    // 8192
  float* Sinv    = ws + 671872;    // 128
  float* ctxpart = ws + 672000;    // 262144  [th][b][h][1024]

  hipLaunchKernelGGL(k_q,      dim3(64),  dim3(256), 0, stream, cell, Wq, bq, qbuf);
  hipLaunchKernelGGL(k_qwk,    dim3(64),  dim3(256), 0, stream, qbuf, Wk, bk, qWkT, qbk);
  hipLaunchKernelGGL(k_scores, dim3(512), dim3(256), 0, stream, hid, qWkT, qbk, mask, probsT, Spart);
  hipLaunchKernelGGL(k_sinv,   dim3(1),   dim3(128), 0, stream, Spart, Sinv);
  hipLaunchKernelGGL(k_ctx,    dim3(256), dim3(256), 0, stream, hid, probsT, ctxpart);
  hipLaunchKernelGGL(k_out,    dim3(64),  dim3(256), 0, stream, Wv, bv, ctxpart, Sinv, out);
}

// Round 3
// 295.394 us; speedup vs baseline: 1.2695x; 1.0302x over previous
//
#include <hip/hip_runtime.h>
#include <math.h>

#define BB 8
#define TT 4096
#define TP1 4097
#define HH 1024
#define NHD 16

__device__ __forceinline__ float dot4(const float4& a, const float4& b) {
  return a.x*b.x + a.y*b.y + a.z*b.z + a.w*b.w;
}

// ---------------- K1: qbuf[b][j] = 0.125*(cell[b,:]·Wq[j,:] + bq[j]) ----------------
// grid 256 (j-tiles of 4), block 256 = 4 jj-waves x 64 lanes
__global__ __launch_bounds__(256) void k_q(const float* __restrict__ cell,
                                           const float* __restrict__ Wq,
                                           const float* __restrict__ bq,
                                           float* __restrict__ qbuf) {
  __shared__ float cs[BB * HH];  // 32 KB
  int tid = threadIdx.x;
  #pragma unroll
  for (int m = 0; m < 8; m++) {
    int idx4 = tid + (m << 8);
    ((float4*)cs)[idx4] = ((const float4*)cell)[idx4];
  }
  __syncthreads();
  int jj = tid >> 6, lane = tid & 63;
  int j = blockIdx.x * 4 + jj;
  float acc[BB];
  #pragma unroll
  for (int b = 0; b < BB; b++) acc[b] = 0.f;
  #pragma unroll
  for (int k = 0; k < 4; k++) {
    int i = (k << 8) + (lane << 2);
    float4 w = *(const float4*)&Wq[(size_t)j * HH + i];
    #pragma unroll
    for (int b = 0; b < BB; b++) acc[b] += dot4(w, *(const float4*)&cs[b * HH + i]);
  }
  #pragma unroll
  for (int b = 0; b < BB; b++) {
    acc[b] += __shfl_xor(acc[b], 1);  acc[b] += __shfl_xor(acc[b], 2);
    acc[b] += __shfl_xor(acc[b], 4);  acc[b] += __shfl_xor(acc[b], 8);
    acc[b] += __shfl_xor(acc[b], 16); acc[b] += __shfl_xor(acc[b], 32);
  }
  if (lane == 0) {
    float bqv = bq[j];
    #pragma unroll
    for (int b = 0; b < BB; b++) qbuf[b * HH + j] = 0.125f * (acc[b] + bqv);
  }
}

// ---------------- K2: qWkT[b][i][h] = sum_d qbuf[b][h*64+d]*Wk[h*64+d][i] ----------------
// grid 256 = h(16) x ic(16); block 256 = 4 d-groups x 64 i-lanes. Also qbk[b][h].
__global__ __launch_bounds__(256) void k_qwk(const float* __restrict__ qbuf,
                                             const float* __restrict__ Wk,
                                             const float* __restrict__ bk,
                                             float* __restrict__ qWkT,
                                             float* __restrict__ qbk) {
  __shared__ float q_s[BB * 64];
  __shared__ float red[4 * 64 * 9];  // padded +1
  int tid = threadIdx.x;
  int h = blockIdx.x >> 4, ic = blockIdx.x & 15;
  if (tid < 128) {
    int b = tid >> 4, dq = tid & 15;
    ((float4*)q_s)[tid] = ((const float4*)qbuf)[(b << 8) + (h << 4) + dq];
  }
  __syncthreads();
  int dg = tid >> 6, lane = tid & 63;
  int i = (ic << 6) + lane;
  float acc[BB];
  #pragma unroll
  for (int b = 0; b < BB; b++) acc[b] = 0.f;
  #pragma unroll
  for (int dd = 0; dd < 16; dd++) {
    int d = (dg << 4) + dd;
    float wk = Wk[(size_t)((h << 6) + d) * HH + i];
    #pragma unroll
    for (int b = 0; b < BB; b++) acc[b] += q_s[(b << 6) + d] * wk;
  }
  #pragma unroll
  for (int b = 0; b < BB; b++) red[((dg << 6) + lane) * 9 + b] = acc[b];
  __syncthreads();
  #pragma unroll
  for (int r = 0; r < 2; r++) {
    int o = tid + (r << 8);           // 512 outputs = 64 i x 8 b
    int il = o >> 3, b = o & 7;
    float s = 0.f;
    #pragma unroll
    for (int g = 0; g < 4; g++) s += red[((g << 6) + il) * 9 + b];
    qWkT[((size_t)(b << 10) + (ic << 6) + il) * NHD + h] = s;
  }
  if (ic == 0 && tid < 8) {
    float s = 0.f;
    for (int d = 0; d < 64; d++) s += q_s[(tid << 6) + d] * bk[(h << 6) + d];
    qbk[tid * NHD + h] = s;
  }
}

// ---------------- K3: scores -> unnormalized exp, probsT[b][t][16] + Spart ----------------
// grid 512 = b(8) x tile(64 rows); block 256 = 4 waves; lane = t-row (64),
// wave w owns cols [w*16, w*16+16) of each 64-col chunk -> qWkT loads wave-uniform (scalar).
// kv staged via double-buffered padded LDS tile (64x68), coalesced global loads.
__device__ __forceinline__ void stage_tile(const float* __restrict__ src, float* dst, int tid) {
  #pragma unroll
  for (int m = 0; m < 4; m++) {
    int idx = tid + (m << 8);
    int r = idx >> 4, c4 = idx & 15;
    *(float4*)&dst[r * 68 + (c4 << 2)] = *(const float4*)&src[(size_t)r * HH + (c4 << 2)];
  }
}

__device__ __forceinline__ void compute_chunk(const float* kv_s, const float* __restrict__ qb,
                                              int lane, int w, float* acc) {
  float4 kv[4];
  #pragma unroll
  for (int cq = 0; cq < 4; cq++)
    kv[cq] = *(const float4*)&kv_s[lane * 68 + (w << 4) + (cq << 2)];
  #pragma unroll
  for (int cq = 0; cq < 4; cq++) {
    const float* qp = qb + (cq << 6);
    #pragma unroll
    for (int h = 0; h < NHD; h++)
      acc[h] += kv[cq].x * qp[h] + kv[cq].y * qp[NHD + h] +
                kv[cq].z * qp[2 * NHD + h] + kv[cq].w * qp[3 * NHD + h];
  }
}

__global__ __launch_bounds__(256) void k_scores(const float* __restrict__ hid,
                                                const float* __restrict__ qWkT,
                                                const float* __restrict__ qbk,
                                                const int* __restrict__ mask,
                                                float* __restrict__ probsT,
                                                float* __restrict__ Spart) {
  __shared__ float kv0[64 * 68];   // 17.4 KB (overlaid by red after the loop)
  __shared__ float kv1[64 * 68];   // 17.4 KB (overlaid by e_sh)
  __shared__ float qbk_s[NHD];
  int tid = threadIdx.x;
  int b = blockIdx.x >> 6, tile = blockIdx.x & 63;
  int t0 = tile << 6;
  if (tid < NHD) qbk_s[tid] = qbk[b * NHD + tid];
  int w = __builtin_amdgcn_readfirstlane(tid >> 6);
  int lane = tid & 63;
  const float* src = hid + ((size_t)(b * TP1) + t0) * HH;
  const float* qB = qWkT + (((size_t)(b << 10) + (w << 4)) << 4);
  float acc[NHD];
  #pragma unroll
  for (int h = 0; h < NHD; h++) acc[h] = 0.f;

  stage_tile(src, kv0, tid);
  __syncthreads();
  for (int cc = 0; cc < 16; cc += 2) {
    stage_tile(src + ((cc + 1) << 6), kv1, tid);
    compute_chunk(kv0, qB + ((cc << 6) << 4), lane, w, acc);
    __syncthreads();
    if (cc + 2 < 16) stage_tile(src + ((cc + 2) << 6), kv0, tid);
    compute_chunk(kv1, qB + (((cc + 1) << 6) << 4), lane, w, acc);
    __syncthreads();
  }

  float* red = kv0;    // 4096 floats needed, 4352 available
  float* e_sh = kv1;   // 1024 floats needed
  #pragma unroll
  for (int h4 = 0; h4 < 4; h4++)
    *(float4*)&red[((w << 6) + lane) * NHD + (h4 << 2)] =
        make_float4(acc[h4 * 4], acc[h4 * 4 + 1], acc[h4 * 4 + 2], acc[h4 * 4 + 3]);
  __syncthreads();
  int row = tid >> 2, hq = tid & 3;
  float4 s = make_float4(0.f, 0.f, 0.f, 0.f);
  #pragma unroll
  for (int ww = 0; ww < 4; ww++) {
    float4 r = *(const float4*)&red[((ww << 6) + row) * NHD + (hq << 2)];
    s.x += r.x; s.y += r.y; s.z += r.z; s.w += r.w;
  }
  int mk = mask[b * TT + t0 + row];
  float4 e;
  e.x = mk ? __expf(s.x + qbk_s[hq * 4 + 0]) : 0.f;
  e.y = mk ? __expf(s.y + qbk_s[hq * 4 + 1]) : 0.f;
  e.z = mk ? __expf(s.z + qbk_s[hq * 4 + 2]) : 0.f;
  e.w = mk ? __expf(s.w + qbk_s[hq * 4 + 3]) : 0.f;
  *(float4*)&probsT[((size_t)(b * TT + t0 + row)) * NHD + (hq << 2)] = e;
  *(float4*)&e_sh[row * NHD + (hq << 2)] = e;
  __syncthreads();
  if (tid < 64) {
    int g = tid >> 4, h2 = tid & 15;
    float s2 = 0.f;
    #pragma unroll
    for (int j = 0; j < 16; j++) s2 += e_sh[((g + (j << 2)) << 4) + h2];
    s2 += __shfl_xor(s2, 16);
    s2 += __shfl_xor(s2, 32);
    if (tid < 16) Spart[(size_t)((b << 6) + tile) * NHD + h2] = s2;
  }
}

// ---------------- K4: Sinv[b][h] = 1 / sum_tiles Spart ----------------
__global__ void k_sinv(const float* __restrict__ Spart, float* __restrict__ Sinv) {
  int tid = threadIdx.x;  // 128
  float s = 0.f;
  for (int c = 0; c < 64; c++) s += Spart[(size_t)((tid >> 4) * 64 + c) * NHD + (tid & 15)];
  Sinv[tid] = 1.f / s;
}

// ---------------- K5: ctxin[b][h][i] += sum_t e[t][h]*kv[t][i] (unnormalized) ----------------
// grid 512 = b(8) x ic(4) x th(16); block 256 = 4 waves; lane = i-quad (float4, 1KB/wave load),
// wave t-phase = th*4+w -> probsT row wave-uniform (scalar loads). LDS pair-reduce + atomics.
__global__ __launch_bounds__(256) void k_ctx(const float* __restrict__ hid,
                                             const float* __restrict__ probsT,
                                             float* __restrict__ ctxin) {
  __shared__ float red2[2][64 * 64];  // 32 KB
  int tid = threadIdx.x;
  int b = blockIdx.x >> 6, ic = (blockIdx.x >> 4) & 3, th = blockIdx.x & 15;
  int w = __builtin_amdgcn_readfirstlane(tid >> 6);
  int lane = tid & 63;
  int t0 = (th << 2) + w;
  const float* kvp = hid + (size_t)b * TP1 * HH + (ic << 8) + (lane << 2);
  const float* pb = probsT + ((size_t)(b << 12) + t0) * NHD;
  float4 acc4[NHD];
  #pragma unroll
  for (int h = 0; h < NHD; h++) acc4[h] = make_float4(0.f, 0.f, 0.f, 0.f);
  #pragma unroll 4
  for (int it = 0; it < 64; it++) {
    int t = it << 6;
    float4 kv = *(const float4*)&kvp[(size_t)(t0 + t) * HH];
    const float* pp = pb + (size_t)t * NHD;
    #pragma unroll
    for (int h = 0; h < NHD; h++) {
      float p = pp[h];
      acc4[h].x += kv.x * p; acc4[h].y += kv.y * p;
      acc4[h].z += kv.z * p; acc4[h].w += kv.w * p;
    }
  }
  if (w < 2) {
    #pragma unroll
    for (int h = 0; h < NHD; h++)
      *(float4*)&red2[w][(lane << 6) + (h << 2)] = acc4[h];
  }
  __syncthreads();
  if (w >= 2) {
    #pragma unroll
    for (int h = 0; h < NHD; h++) {
      float4 r = *(const float4*)&red2[w - 2][(lane << 6) + (h << 2)];
      r.x += acc4[h].x; r.y += acc4[h].y; r.z += acc4[h].z; r.w += acc4[h].w;
      *(float4*)&red2[w - 2][(lane << 6) + (h << 2)] = r;
    }
  }
  __syncthreads();
  #pragma unroll
  for (int j = 0; j < 4; j++) {
    int k = tid + (j << 8);  // 1024 float4 = 64 i-quads x 16 h
    float4 a = ((const float4*)red2[0])[k];
    float4 c2 = ((const float4*)red2[1])[k];
    int li = k >> 4, h = k & 15;
    float* dst = ctxin + (((size_t)(b << 4) + h) << 10) + (ic << 8) + (li << 2);
    atomicAdd(dst + 0, a.x + c2.x);
    atomicAdd(dst + 1, a.y + c2.y);
    atomicAdd(dst + 2, a.z + c2.z);
    atomicAdd(dst + 3, a.w + c2.w);
  }
}

// ---------------- K6: out[b][h*64+(j%64)] = Sinv[b][h]*(Wv[j,:]·ctxin[b][h][:]) + bv[j] ----------------
// grid 256 (j-tiles of 4, within one head); block 256 = 4 jj-waves x 64 lanes
__global__ __launch_bounds__(256) void k_out(const float* __restrict__ Wv,
                                             const float* __restrict__ bv,
                                             const float* __restrict__ ctxin,
                                             const float* __restrict__ Sinv,
                                             float* __restrict__ out) {
  __shared__ float cs[BB * HH];  // 32 KB
  int tid = threadIdx.x;
  int h = blockIdx.x >> 4;
  int j0 = blockIdx.x * 4;
  #pragma unroll
  for (int m = 0; m < 8; m++) {
    int idx4 = tid + (m << 8);
    int b = idx4 >> 8, i4 = idx4 & 255;
    ((float4*)cs)[idx4] = ((const float4*)ctxin)[(((b << 4) + h) << 8) + i4];
  }
  __syncthreads();
  int jj = tid >> 6, lane = tid & 63;
  int j = j0 + jj;
  float acc[BB];
  #pragma unroll
  for (int b = 0; b < BB; b++) acc[b] = 0.f;
  #pragma unroll
  for (int k = 0; k < 4; k++) {
    int i = (k << 8) + (lane << 2);
    float4 w = *(const float4*)&Wv[(size_t)j * HH + i];
    #pragma unroll
    for (int b = 0; b < BB; b++) acc[b] += dot4(w, *(const float4*)&cs[b * HH + i]);
  }
  #pragma unroll
  for (int b = 0; b < BB; b++) {
    acc[b] += __shfl_xor(acc[b], 1);  acc[b] += __shfl_xor(acc[b], 2);
    acc[b] += __shfl_xor(acc[b], 4);  acc[b] += __shfl_xor(acc[b], 8);
    acc[b] += __shfl_xor(acc[b], 16); acc[b] += __shfl_xor(acc[b], 32);
  }
  if (lane == 0) {
    float bvj = bv[j];
    #pragma unroll
    for (int b = 0; b < BB; b++)
      out[b * HH + j] = Sinv[b * NHD + h] * acc[b] + bvj;
  }
}

extern "C" void kernel_launch(void* const* d_in, const int* in_sizes, int n_in,
                              void* d_out, int out_size, void* d_ws, size_t ws_size,
                              hipStream_t stream) {
  const float* hid  = (const float*)d_in[0];  // (8, 4097, 1024)
  const float* cell = (const float*)d_in[1];  // (8, 1024)
  const float* Wq   = (const float*)d_in[2];
  const float* bq   = (const float*)d_in[3];
  const float* Wk   = (const float*)d_in[4];
  const float* bk   = (const float*)d_in[5];
  const float* Wv   = (const float*)d_in[6];
  const float* bv   = (const float*)d_in[7];
  const int*  mask  = (const int*)d_in[8];    // (8, 4096)
  float* out = (float*)d_out;                 // (8, 1024)

  float* ws = (float*)d_ws;
  float* qbuf    = ws;             // 8192
  float* qWkT    = ws + 8192;      // 131072  [b][i][16]
  float* qbk     = ws + 139264;    // 128
  float* probsT  = ws + 139392;    // 524288  [b][t][16] unnormalized exp
  float* Spart   = ws + 663680;    // 8192
  float* Sinv    = ws + 671872;    // 128
  float* ctxin   = ws + 672000;    // 131072  [b][h][1024] (atomic accum)

  hipMemsetAsync(ctxin, 0, (size_t)BB * NHD * HH * sizeof(float), stream);
  hipLaunchKernelGGL(k_q,      dim3(256), dim3(256), 0, stream, cell, Wq, bq, qbuf);
  hipLaunchKernelGGL(k_qwk,    dim3(256), dim3(256), 0, stream, qbuf, Wk, bk, qWkT, qbk);
  hipLaunchKernelGGL(k_scores, dim3(512), dim3(256), 0, stream, hid, qWkT, qbk, mask, probsT, Spart);
  hipLaunchKernelGGL(k_sinv,   dim3(1),   dim3(128), 0, stream, Spart, Sinv);
  hipLaunchKernelGGL(k_ctx,    dim3(512), dim3(256), 0, stream, hid, probsT, ctxin);
  hipLaunchKernelGGL(k_out,    dim3(256), dim3(256), 0, stream, Wv, bv, ctxin, Sinv, out);
}